// Round 6
// baseline (343.898 us; speedup 1.0000x reference)
//
#include <hip/hip_runtime.h>

// GroupedVectorSA (gfx950) — ROUND 6: coalesced B-fragments + coalesced/prefetched gathers.
// k_prep: weights -> bf16 FRAGMENT-LINEAR layout ([nt][kk][lane][8], lane=quad*16+ln15)
//         so every MFMA B-load is base+lane*16 (1KB/instr coalesced).
// k_qkv : q/k/v GEMM (MFMA), fp32 feats -> bf16 q/k/v.
// k_main: fused pos-MLPs + relation + logits + softmax + weighted sum, fp32 out.

typedef __attribute__((ext_vector_type(8))) short bf16x8_t;
typedef __attribute__((ext_vector_type(4))) float f32x4_t;

#define BN_EPS 1e-5f

__device__ __forceinline__ float b2f(unsigned int b) {
    union { unsigned int u; float f; } x; x.u = b << 16; return x.f;
}
__device__ __forceinline__ unsigned short f2b(float f) {      // RNE fp32->bf16
    union { float f; unsigned int u; } x; x.f = f;
    return (unsigned short)((x.u + 0x7fffu + ((x.u >> 16) & 1u)) >> 16);
}
__device__ __forceinline__ unsigned int relpair(unsigned int kb, unsigned int qb,
                                                unsigned int pm_, unsigned int pb_) {
    float r0 = (b2f(kb & 0xffffu) - b2f(qb & 0xffffu)) * b2f(pm_ & 0xffffu) + b2f(pb_ & 0xffffu);
    float r1 = (b2f(kb >> 16)     - b2f(qb >> 16))     * b2f(pm_ >> 16)     + b2f(pb_ >> 16);
    return (unsigned int)f2b(r0) | ((unsigned int)f2b(r1) << 16);
}

// ---------------------------------------------------------------------------
// K0: 5 fp32 [256][256] weights -> bf16 fragment-linear. grid=5*256, blk=256.
// o = nt*4096 + kk*512 + lane*8 + j ; value = W[k][n], k=kk*32+quad*8+j, n=nt*16+ln15.
// ---------------------------------------------------------------------------
__global__ __launch_bounds__(256) void k_prep(
    const float* __restrict__ wq, const float* __restrict__ wk,
    const float* __restrict__ wv, const float* __restrict__ pm2,
    const float* __restrict__ pb2, unsigned short* __restrict__ wsT)
{
    int mat = blockIdx.x >> 8;
    int o   = (blockIdx.x & 255) * 256 + threadIdx.x;
    const float* s = (mat == 0) ? wq : (mat == 1) ? wk : (mat == 2) ? wv
                     : (mat == 3) ? pm2 : pb2;
    int nt = o >> 12, kk = (o >> 9) & 7, lane = (o >> 3) & 63, j = o & 7;
    int k = kk * 32 + (lane >> 4) * 8 + j;
    int n = nt * 16 + (lane & 15);
    wsT[mat * 65536 + o] = f2b(s[k * 256 + n]);
}

// ---------------------------------------------------------------------------
// K1: q/k/v GEMM. grid=256 (32-row tiles), blk=256. BN in fp32 epilogue.
// ---------------------------------------------------------------------------
__global__ __launch_bounds__(256, 2) void k_qkv(
    const float* __restrict__ feats,
    const unsigned short* __restrict__ wT,    // [3] frag-linear 65536 each
    const float* __restrict__ bq, const float* __restrict__ bnq,
    const float* __restrict__ bk, const float* __restrict__ bnk,
    const float* __restrict__ bv,
    unsigned short* __restrict__ qkv)         // [3][8192][256] bf16
{
    __shared__ unsigned short A[32][264];
    const int t  = threadIdx.x;
    const int mb = blockIdx.x;

    for (int i = 0; i < 8; ++i) {
        int row = 4 * i + (t >> 6), col = (t & 63) * 4;
        float4 f = *(const float4*)(feats + (mb * 32 + row) * 256 + col);
        unsigned int lo = (unsigned int)f2b(f.x) | ((unsigned int)f2b(f.y) << 16);
        unsigned int hi = (unsigned int)f2b(f.z) | ((unsigned int)f2b(f.w) << 16);
        *(uint2*)&A[row][col] = make_uint2(lo, hi);
    }
    __syncthreads();

    const int lane = t & 63, w = t >> 6;
    const int ln15 = lane & 15, quad = lane >> 4;
    const int mt = w & 1, nh = w >> 1;

    bf16x8_t afr[8];
    #pragma unroll
    for (int kk = 0; kk < 8; ++kk)
        afr[kk] = *(const bf16x8_t*)&A[mt * 16 + ln15][kk * 32 + quad * 8];

    const f32x4_t fzero = {0.f, 0.f, 0.f, 0.f};

    for (int widx = 0; widx < 3; ++widx) {
        const unsigned short* W = wT + widx * 65536;
        const float* bias = (widx == 0) ? bq : (widx == 1) ? bk : bv;
        const float* bn   = (widx == 0) ? bnq : (widx == 1) ? bnk : nullptr;
        unsigned short* dst = qkv + (size_t)widx * 8192 * 256;

        for (int ntg = 0; ntg < 2; ++ntg) {
            f32x4_t acc[4];
            for (int j = 0; j < 4; ++j) acc[j] = fzero;
            #pragma unroll
            for (int kk = 0; kk < 8; ++kk) {
                #pragma unroll
                for (int t4 = 0; t4 < 4; ++t4) {
                    int nt = nh * 8 + ntg * 4 + t4;
                    bf16x8_t bfr = *(const bf16x8_t*)(W + ((nt * 8 + kk) * 64 + lane) * 8);
                    acc[t4] = __builtin_amdgcn_mfma_f32_16x16x32_bf16(afr[kk], bfr, acc[t4], 0, 0, 0);
                }
            }
            for (int t4 = 0; t4 < 4; ++t4) {
                int nt = nh * 8 + ntg * 4 + t4;
                int c  = nt * 16 + ln15;
                float bb = bias[c];
                float sc = 1.f, mu = 0.f, be = 0.f;
                if (bn) {
                    sc = bn[c] / sqrtf(bn[768 + c] + BN_EPS);
                    be = bn[256 + c];
                    mu = bn[512 + c];
                }
                for (int r = 0; r < 4; ++r) {
                    float y = acc[t4][r] + bb;
                    if (bn) y = fmaxf((y - mu) * sc + be, 0.f);
                    dst[(mb * 32 + mt * 16 + quad * 4 + r) * 256 + c] = f2b(y);
                }
            }
        }
    }
}

// ---------------------------------------------------------------------------
// K2: fused main. 1 WG = 4 points (64 rows). blk=256, grid=2048.
// ---------------------------------------------------------------------------
__global__ __launch_bounds__(256, 2) void k_main(
    const float* __restrict__ coords,
    const int*   __restrict__ index,
    const unsigned short* __restrict__ qm,
    const unsigned short* __restrict__ km,
    const unsigned short* __restrict__ vm,
    const unsigned short* __restrict__ pmw2F,   // frag-linear
    const unsigned short* __restrict__ pbw2F,   // frag-linear
    const float* __restrict__ pm_w1, const float* __restrict__ pm_b1,
    const float* __restrict__ pm_bn, const float* __restrict__ pm_b2,
    const float* __restrict__ pb_w1, const float* __restrict__ pb_b1,
    const float* __restrict__ pb_bn, const float* __restrict__ pb_b2,
    const float* __restrict__ we_w1, const float* __restrict__ we_b1,
    const float* __restrict__ we_bn, const float* __restrict__ we_w2,
    const float* __restrict__ we_b2,
    float* __restrict__ out)
{
    __shared__ unsigned short bufR[64][264];   // pem, then relation r (bf16)
    __shared__ unsigned short bufP[64][264];   // peb (+pb_b2) (bf16)
    __shared__ __align__(16) char uni[8448];   // Wpm/Wpb -> we1T/us_/lg_
    float (*Wpm)[256] = (float(*)[256])uni;
    float (*Wpb)[256] = (float(*)[256])(uni + 4096);
    unsigned short (*we1T)[264] = (unsigned short(*)[264])uni;
    float (*us_)[8] = (float(*)[8])(uni + 4224);
    float (*lg_)[8] = (float(*)[8])(uni + 6272);
    __shared__ float posA[64][4];
    __shared__ int   rowg[64];
    __shared__ float swe[8], dwe[8], web2[8];
    __shared__ float we2s[8][8];

    const int t  = threadIdx.x;
    const int P0 = blockIdx.x * 4;
    const int b  = P0 >> 12;

    // ---- prefetch: k-row gather (coalesced dwordx4, 4 lanes/row), pre-barrier ----
    const int m3  = t >> 2;                    // row 0..63
    const int Pg3 = P0 + (m3 >> 4);
    const int rg3 = (b << 12) + index[Pg3 * 16 + (m3 & 15)];
    const int c3  = (t & 3) * 8;               // short offset base within row
    uint4 kpre[8];
    {
        const unsigned short* krow = km + rg3 * 256 + c3;
        #pragma unroll
        for (int i = 0; i < 8; ++i) kpre[i] = *(const uint4*)(krow + 32 * i);
    }

    // ---- phase 0 ----
    if (t < 64) {
        int p = t >> 4, s = t & 15;
        int Pg = P0 + p;
        int rg = (b << 12) + index[Pg * 16 + s];
        rowg[t] = rg;
        posA[t][0] = coords[Pg * 3 + 0] - coords[rg * 3 + 0];
        posA[t][1] = coords[Pg * 3 + 1] - coords[rg * 3 + 1];
        posA[t][2] = coords[Pg * 3 + 2] - coords[rg * 3 + 2];
        posA[t][3] = 0.f;
    }
    {
        int c = t;
        float sc = pm_bn[c] / sqrtf(pm_bn[768 + c] + BN_EPS);
        Wpm[0][c] = pm_w1[c] * sc;
        Wpm[1][c] = pm_w1[256 + c] * sc;
        Wpm[2][c] = pm_w1[512 + c] * sc;
        Wpm[3][c] = (pm_b1[c] - pm_bn[512 + c]) * sc + pm_bn[256 + c];
        sc = pb_bn[c] / sqrtf(pb_bn[768 + c] + BN_EPS);
        Wpb[0][c] = pb_w1[c] * sc;
        Wpb[1][c] = pb_w1[256 + c] * sc;
        Wpb[2][c] = pb_w1[512 + c] * sc;
        Wpb[3][c] = (pb_b1[c] - pb_bn[512 + c]) * sc + pb_bn[256 + c];
    }
    if (t < 8) {
        float sc = we_bn[t] / sqrtf(we_bn[24 + t] + BN_EPS);
        swe[t]  = sc;
        dwe[t]  = (we_b1[t] - we_bn[16 + t]) * sc + we_bn[8 + t];
        web2[t] = we_b2[t];
    }
    if (t < 64) we2s[t >> 3][t & 7] = we_w2[t];
    __syncthreads();

    const int lane = t & 63, w = t >> 6;
    const int ln15 = lane & 15, quad = lane >> 4;
    const int mrow = w * 16 + ln15;
    const f32x4_t fzero = {0.f, 0.f, 0.f, 0.f};

    // ---- phases 1+2: pos-MLPs. pass0 = peb -> bufP, pass1 = pem -> bufR ----
    {
        float p_[4][3];
        #pragma unroll
        for (int mt = 0; mt < 4; ++mt) {
            p_[mt][0] = posA[mt * 16 + ln15][0];
            p_[mt][1] = posA[mt * 16 + ln15][1];
            p_[mt][2] = posA[mt * 16 + ln15][2];
        }
        for (int pass = 0; pass < 2; ++pass) {
            const float* Wl = pass ? &Wpm[0][0] : &Wpb[0][0];
            const unsigned short* W2F = pass ? pmw2F : pbw2F;
            const float* bias2 = pass ? pm_b2 : pb_b2;
            unsigned short (*obuf)[264] = pass ? bufR : bufP;

            bf16x8_t hfr[4][8];
            #pragma unroll
            for (int kk = 0; kk < 8; ++kk) {
                int cb = kk * 32 + quad * 8;
                float4 w0a = *(const float4*)&Wl[cb];
                float4 w0b = *(const float4*)&Wl[cb + 4];
                float4 w1a = *(const float4*)&Wl[256 + cb];
                float4 w1b = *(const float4*)&Wl[256 + cb + 4];
                float4 w2a = *(const float4*)&Wl[512 + cb];
                float4 w2b = *(const float4*)&Wl[512 + cb + 4];
                float4 w3a = *(const float4*)&Wl[768 + cb];
                float4 w3b = *(const float4*)&Wl[768 + cb + 4];
                #pragma unroll
                for (int mt = 0; mt < 4; ++mt) {
                    float q0 = p_[mt][0], q1 = p_[mt][1], q2 = p_[mt][2];
                    bf16x8_t hv;
                    hv[0] = (short)f2b(fmaxf(q0 * w0a.x + q1 * w1a.x + q2 * w2a.x + w3a.x, 0.f));
                    hv[1] = (short)f2b(fmaxf(q0 * w0a.y + q1 * w1a.y + q2 * w2a.y + w3a.y, 0.f));
                    hv[2] = (short)f2b(fmaxf(q0 * w0a.z + q1 * w1a.z + q2 * w2a.z + w3a.z, 0.f));
                    hv[3] = (short)f2b(fmaxf(q0 * w0a.w + q1 * w1a.w + q2 * w2a.w + w3a.w, 0.f));
                    hv[4] = (short)f2b(fmaxf(q0 * w0b.x + q1 * w1b.x + q2 * w2b.x + w3b.x, 0.f));
                    hv[5] = (short)f2b(fmaxf(q0 * w0b.y + q1 * w1b.y + q2 * w2b.y + w3b.y, 0.f));
                    hv[6] = (short)f2b(fmaxf(q0 * w0b.z + q1 * w1b.z + q2 * w2b.z + w3b.z, 0.f));
                    hv[7] = (short)f2b(fmaxf(q0 * w0b.w + q1 * w1b.w + q2 * w2b.w + w3b.w, 0.f));
                    hfr[mt][kk] = hv;
                }
            }
            #pragma unroll
            for (int ntl = 0; ntl < 4; ++ntl) {
                int nt = w * 4 + ntl;
                f32x4_t acc[4];
                for (int j = 0; j < 4; ++j) acc[j] = fzero;
                #pragma unroll
                for (int kk = 0; kk < 8; ++kk) {
                    bf16x8_t bfr = *(const bf16x8_t*)(W2F + ((nt * 8 + kk) * 64 + lane) * 8);
                    #pragma unroll
                    for (int mt = 0; mt < 4; ++mt)
                        acc[mt] = __builtin_amdgcn_mfma_f32_16x16x32_bf16(hfr[mt][kk], bfr, acc[mt], 0, 0, 0);
                }
                int c = nt * 16 + ln15;
                float bb = bias2[c];
                for (int mt = 0; mt < 4; ++mt)
                    for (int r = 0; r < 4; ++r)
                        obuf[mt * 16 + quad * 4 + r][c] = f2b(acc[mt][r] + bb);
            }
        }
    }
    __syncthreads();

    // ---- phase 3: r = (k_g - q) * pem + peb (uint4 lanes; k prefetched) ----
    if (t < 64) {                               // we1T fill (uni reuse after barrier)
        int g = t >> 3, j8 = t & 7;
        for (int i = 0; i < 32; ++i) {
            int c = j8 * 32 + i;
            we1T[g][c] = f2b(we_w1[c * 8 + g]);
        }
    }
    {
        const unsigned short* qrow = qm + Pg3 * 256 + c3;
        #pragma unroll
        for (int i = 0; i < 8; ++i) {
            int c = c3 + 32 * i;
            uint4 qb  = *(const uint4*)(qrow + 32 * i);
            uint4 pmv = *(const uint4*)&bufR[m3][c];
            uint4 pbv = *(const uint4*)&bufP[m3][c];
            uint4 r;
            r.x = relpair(kpre[i].x, qb.x, pmv.x, pbv.x);
            r.y = relpair(kpre[i].y, qb.y, pmv.y, pbv.y);
            r.z = relpair(kpre[i].z, qb.z, pmv.z, pbv.z);
            r.w = relpair(kpre[i].w, qb.w, pmv.w, pbv.w);
            *(uint4*)&bufR[m3][c] = r;
        }
    }
    __syncthreads();

    // ---- phase 4a: logits GEMM (r @ we_w1, K=256, N=8; cols 8..15 zero) ----
    {
        const bf16x8_t bz = {0, 0, 0, 0, 0, 0, 0, 0};
        f32x4_t lacc = fzero;
        #pragma unroll
        for (int kk = 0; kk < 8; ++kk) {
            bf16x8_t afr = *(const bf16x8_t*)&bufR[mrow][kk * 32 + quad * 8];
            bf16x8_t bfr = bz;
            if (ln15 < 8) bfr = *(const bf16x8_t*)&we1T[ln15][kk * 32 + quad * 8];
            lacc = __builtin_amdgcn_mfma_f32_16x16x32_bf16(afr, bfr, lacc, 0, 0, 0);
        }
        if (ln15 < 8) {
            float sc = swe[ln15], dd = dwe[ln15];
            for (int r = 0; r < 4; ++r)
                us_[w * 16 + quad * 4 + r][ln15] = fmaxf(lacc[r] * sc + dd, 0.f);
        }
    }
    __syncthreads();

    // ---- phase 4b: logits = u @ we_w2 + we_b2 ----
    if (t < 64) {
        float uv[8];
        for (int gp = 0; gp < 8; ++gp) uv[gp] = us_[t][gp];
        for (int g = 0; g < 8; ++g) {
            float l = web2[g];
            for (int gp = 0; gp < 8; ++gp) l += uv[gp] * we2s[gp][g];
            lg_[t][g] = l;
        }
    }
    __syncthreads();

    // ---- phase 4c: softmax over 16 neighbors ----
    if (t < 32) {
        int p = t >> 3, g = t & 7;
        float mx = -1e30f;
        for (int s = 0; s < 16; ++s) mx = fmaxf(mx, lg_[p * 16 + s][g]);
        float e[16], sum = 0.f;
        for (int s = 0; s < 16; ++s) { e[s] = __expf(lg_[p * 16 + s][g] - mx); sum += e[s]; }
        float inv = 1.f / sum;
        for (int s = 0; s < 16; ++s) lg_[p * 16 + s][g] = e[s] * inv;
    }
    __syncthreads();

    // ---- phase 5: out[p][c] = sum_s w[s][g] * (v_g[s][c] + peb[s][c]) ----
    {
        int p = t >> 6;
        int c = (t & 63) * 4;
        int g = c >> 5;
        float a0 = 0.f, a1 = 0.f, a2 = 0.f, a3 = 0.f;
        for (int s = 0; s < 16; ++s) {
            int m = p * 16 + s;
            float wv_ = lg_[m][g];
            uint2 v4 = *(const uint2*)(vm + rowg[m] * 256 + c);
            uint2 p4 = *(const uint2*)&bufP[m][c];
            a0 += wv_ * (b2f(v4.x & 0xffffu) + b2f(p4.x & 0xffffu));
            a1 += wv_ * (b2f(v4.x >> 16)     + b2f(p4.x >> 16));
            a2 += wv_ * (b2f(v4.y & 0xffffu) + b2f(p4.y & 0xffffu));
            a3 += wv_ * (b2f(v4.y >> 16)     + b2f(p4.y >> 16));
        }
        *(float4*)(out + (size_t)(P0 + p) * 256 + c) = make_float4(a0, a1, a2, a3);
    }
}

// ---------------------------------------------------------------------------
extern "C" void kernel_launch(void* const* d_in, const int* in_sizes, int n_in,
                              void* d_out, int out_size, void* d_ws, size_t ws_size,
                              hipStream_t stream)
{
    const float* feats  = (const float*)d_in[0];
    const float* coords = (const float*)d_in[1];
    const int*   index  = (const int*)d_in[2];
    const float* wq     = (const float*)d_in[3];
    const float* bq     = (const float*)d_in[4];
    const float* bnq    = (const float*)d_in[5];
    const float* wk     = (const float*)d_in[6];
    const float* bk     = (const float*)d_in[7];
    const float* bnk    = (const float*)d_in[8];
    const float* wv     = (const float*)d_in[9];
    const float* bv     = (const float*)d_in[10];
    const float* pm_w1  = (const float*)d_in[11];
    const float* pm_b1  = (const float*)d_in[12];
    const float* pm_bn  = (const float*)d_in[13];
    const float* pm_w2  = (const float*)d_in[14];
    const float* pm_b2  = (const float*)d_in[15];
    const float* pb_w1  = (const float*)d_in[16];
    const float* pb_b1  = (const float*)d_in[17];
    const float* pb_bn  = (const float*)d_in[18];
    const float* pb_w2  = (const float*)d_in[19];
    const float* pb_b2  = (const float*)d_in[20];
    const float* we_w1  = (const float*)d_in[21];
    const float* we_b1  = (const float*)d_in[22];
    const float* we_bn  = (const float*)d_in[23];
    const float* we_w2  = (const float*)d_in[24];
    const float* we_b2  = (const float*)d_in[25];

    unsigned short* qkv = (unsigned short*)d_ws;                 // 12.58 MB
    unsigned short* wsT = qkv + (size_t)3 * 8192 * 256;          // 640 KB

    const size_t need = ((size_t)3 * 8192 * 256 + (size_t)5 * 65536) * 2;
    if (ws_size < need) {
        hipMemsetAsync(d_out, 0, (size_t)out_size * 4, stream);
        return;
    }

    k_prep<<<5 * 256, 256, 0, stream>>>(wq, wk, wv, pm_w2, pb_w2, wsT);
    k_qkv <<<256,     256, 0, stream>>>(feats, wsT, bq, bnq, bk, bnk, bv, qkv);
    k_main<<<2048,    256, 0, stream>>>(coords, index,
                                        qkv,
                                        qkv + (size_t)8192 * 256,
                                        qkv + (size_t)2 * 8192 * 256,
                                        wsT + 3 * 65536,
                                        wsT + 4 * 65536,
                                        pm_w1, pm_b1, pm_bn, pm_b2,
                                        pb_w1, pb_b1, pb_bn, pb_b2,
                                        we_w1, we_b1, we_bn, we_w2, we_b2,
                                        (float*)d_out);
}

// Round 7
// 222.308 us; speedup vs baseline: 1.5469x; 1.5469x over previous
//
#include <hip/hip_runtime.h>

// GroupedVectorSA (gfx950) — ROUND 7: shared h-build, reg-prefetched gathers,
// k_qkv occupancy + coalesced stores.

typedef __attribute__((ext_vector_type(8))) short bf16x8_t;
typedef __attribute__((ext_vector_type(4))) float f32x4_t;

#define BN_EPS 1e-5f

__device__ __forceinline__ float b2f(unsigned int b) {
    union { unsigned int u; float f; } x; x.u = b << 16; return x.f;
}
__device__ __forceinline__ unsigned short f2b(float f) {      // RNE fp32->bf16
    union { float f; unsigned int u; } x; x.f = f;
    return (unsigned short)((x.u + 0x7fffu + ((x.u >> 16) & 1u)) >> 16);
}
__device__ __forceinline__ unsigned int relpair(unsigned int kb, unsigned int qb,
                                                unsigned int pm_, unsigned int pb_) {
    float r0 = (b2f(kb & 0xffffu) - b2f(qb & 0xffffu)) * b2f(pm_ & 0xffffu) + b2f(pb_ & 0xffffu);
    float r1 = (b2f(kb >> 16)     - b2f(qb >> 16))     * b2f(pm_ >> 16)     + b2f(pb_ >> 16);
    return (unsigned int)f2b(r0) | ((unsigned int)f2b(r1) << 16);
}

// ---------------------------------------------------------------------------
// K0: 5 fp32 [256][256] weights -> bf16 fragment-linear (o = nt*4096+kk*512+lane*8+j).
// ---------------------------------------------------------------------------
__global__ __launch_bounds__(256) void k_prep(
    const float* __restrict__ wq, const float* __restrict__ wk,
    const float* __restrict__ wv, const float* __restrict__ pm2,
    const float* __restrict__ pb2, unsigned short* __restrict__ wsT)
{
    int mat = blockIdx.x >> 8;
    int o   = (blockIdx.x & 255) * 256 + threadIdx.x;
    const float* s = (mat == 0) ? wq : (mat == 1) ? wk : (mat == 2) ? wv
                     : (mat == 3) ? pm2 : pb2;
    int nt = o >> 12, kk = (o >> 9) & 7, lane = (o >> 3) & 63, j = o & 7;
    int k = kk * 32 + (lane >> 4) * 8 + j;
    int n = nt * 16 + (lane & 15);
    wsT[mat * 65536 + o] = f2b(s[k * 256 + n]);
}

// ---------------------------------------------------------------------------
// K1: q/k/v GEMM. grid=768 (widx = bid>>8, mb = bid&255), blk=256, 3 blk/CU.
// ---------------------------------------------------------------------------
__global__ __launch_bounds__(256) void k_qkv(
    const float* __restrict__ feats,
    const unsigned short* __restrict__ wT,
    const float* __restrict__ bq, const float* __restrict__ bnq,
    const float* __restrict__ bk, const float* __restrict__ bnk,
    const float* __restrict__ bv,
    unsigned short* __restrict__ qkv)
{
    __shared__ unsigned short A[32][264];     // feats tile, then C tile
    const int t    = threadIdx.x;
    const int widx = blockIdx.x >> 8;
    const int mb   = blockIdx.x & 255;

    for (int i = 0; i < 8; ++i) {
        int row = 4 * i + (t >> 6), col = (t & 63) * 4;
        float4 f = *(const float4*)(feats + (mb * 32 + row) * 256 + col);
        unsigned int lo = (unsigned int)f2b(f.x) | ((unsigned int)f2b(f.y) << 16);
        unsigned int hi = (unsigned int)f2b(f.z) | ((unsigned int)f2b(f.w) << 16);
        *(uint2*)&A[row][col] = make_uint2(lo, hi);
    }
    __syncthreads();

    const int lane = t & 63, w = t >> 6;
    const int ln15 = lane & 15, quad = lane >> 4;
    const int mt = w & 1, nh = w >> 1;

    bf16x8_t afr[8];
    #pragma unroll
    for (int kk = 0; kk < 8; ++kk)
        afr[kk] = *(const bf16x8_t*)&A[mt * 16 + ln15][kk * 32 + quad * 8];

    const unsigned short* W = wT + widx * 65536;
    const float* bias = (widx == 0) ? bq : (widx == 1) ? bk : bv;
    const float* bn   = (widx == 0) ? bnq : (widx == 1) ? bnk : nullptr;
    unsigned short* dst = qkv + (size_t)widx * 8192 * 256;

    const f32x4_t fzero = {0.f, 0.f, 0.f, 0.f};
    f32x4_t acc[8];
    for (int j = 0; j < 8; ++j) acc[j] = fzero;

    #pragma unroll
    for (int kk = 0; kk < 8; ++kk) {
        #pragma unroll
        for (int j = 0; j < 8; ++j) {
            int nt = nh * 8 + j;
            bf16x8_t bfr = *(const bf16x8_t*)(W + ((nt * 8 + kk) * 64 + lane) * 8);
            acc[j] = __builtin_amdgcn_mfma_f32_16x16x32_bf16(afr[kk], bfr, acc[j], 0, 0, 0);
        }
    }

    // epilogue params per col
    float bb[8], sc[8], mu[8], be[8];
    #pragma unroll
    for (int j = 0; j < 8; ++j) {
        int c = (nh * 8 + j) * 16 + ln15;
        bb[j] = bias[c];
        if (bn) {
            sc[j] = bn[c] / sqrtf(bn[768 + c] + BN_EPS);
            be[j] = bn[256 + c];
            mu[j] = bn[512 + c];
        }
    }
    __syncthreads();                           // afr reads complete everywhere
    #pragma unroll
    for (int j = 0; j < 8; ++j) {
        int c = (nh * 8 + j) * 16 + ln15;
        for (int r = 0; r < 4; ++r) {
            float y = acc[j][r] + bb[j];
            if (bn) y = fmaxf((y - mu[j]) * sc[j] + be[j], 0.f);
            A[mt * 16 + quad * 4 + r][c] = f2b(y);
        }
    }
    __syncthreads();
    {
        int row = t >> 3, cc = (t & 7) * 32;
        #pragma unroll
        for (int j = 0; j < 4; ++j) {
            uint4 v = *(const uint4*)&A[row][cc + 8 * j];
            *(uint4*)(dst + (mb * 32 + row) * 256 + cc + 8 * j) = v;
        }
    }
}

// ---------------------------------------------------------------------------
// K2: fused main. 1 WG = 4 points. blk=256, grid=2048, 2 WG/CU.
// ---------------------------------------------------------------------------
__global__ __launch_bounds__(256, 2) void k_main(
    const float* __restrict__ coords,
    const int*   __restrict__ index,
    const unsigned short* __restrict__ qm,
    const unsigned short* __restrict__ km,
    const unsigned short* __restrict__ vm,
    const unsigned short* __restrict__ pmw2F,
    const unsigned short* __restrict__ pbw2F,
    const float* __restrict__ pm_w1, const float* __restrict__ pm_b1,
    const float* __restrict__ pm_bn, const float* __restrict__ pm_b2,
    const float* __restrict__ pb_w1, const float* __restrict__ pb_b1,
    const float* __restrict__ pb_bn, const float* __restrict__ pb_b2,
    const float* __restrict__ we_w1, const float* __restrict__ we_b1,
    const float* __restrict__ we_bn, const float* __restrict__ we_w2,
    const float* __restrict__ we_b2,
    float* __restrict__ out)
{
    __shared__ unsigned short bufR[64][264];   // h0 -> h1 -> pem -> r
    __shared__ unsigned short bufP[64][264];   // peb
    __shared__ __align__(16) char uni[8448];   // Wpm/Wpb -> we1T/us_/lg_
    float (*Wpm)[256] = (float(*)[256])uni;
    float (*Wpb)[256] = (float(*)[256])(uni + 4096);
    unsigned short (*we1T)[264] = (unsigned short(*)[264])uni;
    float (*us_)[8] = (float(*)[8])(uni + 4224);
    float (*lg_)[8] = (float(*)[8])(uni + 6272);
    __shared__ float posA[64][4];
    __shared__ float bias2[2][256];            // [0]=pb_b2 [1]=pm_b2
    __shared__ float swe[8], dwe[8], web2[8];
    __shared__ float we2s[8][8];

    const int t  = threadIdx.x;
    const int P0 = blockIdx.x * 4;
    const int b  = P0 >> 12;

    // ---- register prefetch: k rows (coalesced, 4 lanes/row) ----
    const int m3  = t >> 2;
    const int Pg3 = P0 + (m3 >> 4);
    const int rg3 = (b << 12) + index[Pg3 * 16 + (m3 & 15)];
    const int c3  = (t & 3) * 8;
    uint4 kpre[8];
    {
        const unsigned short* krow = km + rg3 * 256 + c3;
        #pragma unroll
        for (int i = 0; i < 8; ++i) kpre[i] = *(const uint4*)(krow + 32 * i);
    }
    // ---- register prefetch: v rows (8B/lane per s) ----
    const int p5 = t >> 6, c5 = (t & 63) * 4;
    uint2 vpre[16];
    #pragma unroll
    for (int s = 0; s < 16; ++s) {
        int rgv = (b << 12) + index[(P0 + p5) * 16 + s];
        vpre[s] = *(const uint2*)(vm + rgv * 256 + c5);
    }

    // ---- phase 0: params ----
    if (t < 64) {
        int p = t >> 4, s = t & 15;
        int Pg = P0 + p;
        int rg = (b << 12) + index[Pg * 16 + s];
        posA[t][0] = coords[Pg * 3 + 0] - coords[rg * 3 + 0];
        posA[t][1] = coords[Pg * 3 + 1] - coords[rg * 3 + 1];
        posA[t][2] = coords[Pg * 3 + 2] - coords[rg * 3 + 2];
        posA[t][3] = 0.f;
    }
    {
        int c = t;
        float sc = pm_bn[c] / sqrtf(pm_bn[768 + c] + BN_EPS);
        Wpm[0][c] = pm_w1[c] * sc;
        Wpm[1][c] = pm_w1[256 + c] * sc;
        Wpm[2][c] = pm_w1[512 + c] * sc;
        Wpm[3][c] = (pm_b1[c] - pm_bn[512 + c]) * sc + pm_bn[256 + c];
        sc = pb_bn[c] / sqrtf(pb_bn[768 + c] + BN_EPS);
        Wpb[0][c] = pb_w1[c] * sc;
        Wpb[1][c] = pb_w1[256 + c] * sc;
        Wpb[2][c] = pb_w1[512 + c] * sc;
        Wpb[3][c] = (pb_b1[c] - pb_bn[512 + c]) * sc + pb_bn[256 + c];
        bias2[0][c] = pb_b2[c];
        bias2[1][c] = pm_b2[c];
    }
    if (t < 8) {
        float sc = we_bn[t] / sqrtf(we_bn[24 + t] + BN_EPS);
        swe[t]  = sc;
        dwe[t]  = (we_b1[t] - we_bn[16 + t]) * sc + we_bn[8 + t];
        web2[t] = we_b2[t];
    }
    if (t < 64) we2s[t >> 3][t & 7] = we_w2[t];
    __syncthreads();

    const int lane = t & 63, w = t >> 6;
    const int ln15 = lane & 15, quad = lane >> 4;
    const int mrow = w * 16 + ln15;
    const f32x4_t fzero = {0.f, 0.f, 0.f, 0.f};

    const int hc = (t & 127) * 2;              // h-build: this thread's col pair
    const int hm0 = (t >> 7) * 32;             // and row range [hm0, hm0+32)

    // ---- h0 (for peb) -> bufR ----
    {
        float w00 = Wpb[0][hc], w01 = Wpb[0][hc + 1];
        float w10 = Wpb[1][hc], w11 = Wpb[1][hc + 1];
        float w20 = Wpb[2][hc], w21 = Wpb[2][hc + 1];
        float w30 = Wpb[3][hc], w31 = Wpb[3][hc + 1];
        for (int i = 0; i < 32; ++i) {
            int m = hm0 + i;
            float p0 = posA[m][0], p1 = posA[m][1], p2 = posA[m][2];
            float h0 = fmaxf(p0 * w00 + p1 * w10 + p2 * w20 + w30, 0.f);
            float h1 = fmaxf(p0 * w01 + p1 * w11 + p2 * w21 + w31, 0.f);
            *(unsigned int*)&bufR[m][hc] = (unsigned int)f2b(h0) | ((unsigned int)f2b(h1) << 16);
        }
    }
    __syncthreads();

    // ---- pass0 MFMA: peb = h0 @ pb_w2 ----
    f32x4_t acc[4][4];
    for (int a = 0; a < 4; ++a) for (int mt = 0; mt < 4; ++mt) acc[a][mt] = fzero;
    #pragma unroll
    for (int kk = 0; kk < 8; ++kk) {
        bf16x8_t afr[4];
        #pragma unroll
        for (int mt = 0; mt < 4; ++mt)
            afr[mt] = *(const bf16x8_t*)&bufR[mt * 16 + ln15][kk * 32 + quad * 8];
        #pragma unroll
        for (int ntl = 0; ntl < 4; ++ntl) {
            int nt = w * 4 + ntl;
            bf16x8_t bfr = *(const bf16x8_t*)(pbw2F + ((nt * 8 + kk) * 64 + lane) * 8);
            #pragma unroll
            for (int mt = 0; mt < 4; ++mt)
                acc[ntl][mt] = __builtin_amdgcn_mfma_f32_16x16x32_bf16(afr[mt], bfr, acc[ntl][mt], 0, 0, 0);
        }
    }
    __syncthreads();                           // h0 reads done -> bufR reusable
    // peb epilogue -> bufP
    #pragma unroll
    for (int ntl = 0; ntl < 4; ++ntl) {
        int c = (w * 4 + ntl) * 16 + ln15;
        float bb = bias2[0][c];
        for (int mt = 0; mt < 4; ++mt)
            for (int r = 0; r < 4; ++r)
                bufP[mt * 16 + quad * 4 + r][c] = f2b(acc[ntl][mt][r] + bb);
    }
    // h1 (for pem) -> bufR
    {
        float w00 = Wpm[0][hc], w01 = Wpm[0][hc + 1];
        float w10 = Wpm[1][hc], w11 = Wpm[1][hc + 1];
        float w20 = Wpm[2][hc], w21 = Wpm[2][hc + 1];
        float w30 = Wpm[3][hc], w31 = Wpm[3][hc + 1];
        for (int i = 0; i < 32; ++i) {
            int m = hm0 + i;
            float p0 = posA[m][0], p1 = posA[m][1], p2 = posA[m][2];
            float h0 = fmaxf(p0 * w00 + p1 * w10 + p2 * w20 + w30, 0.f);
            float h1 = fmaxf(p0 * w01 + p1 * w11 + p2 * w21 + w31, 0.f);
            *(unsigned int*)&bufR[m][hc] = (unsigned int)f2b(h0) | ((unsigned int)f2b(h1) << 16);
        }
    }
    __syncthreads();

    // ---- pass1 MFMA: pem = h1 @ pm_w2 ----
    for (int a = 0; a < 4; ++a) for (int mt = 0; mt < 4; ++mt) acc[a][mt] = fzero;
    #pragma unroll
    for (int kk = 0; kk < 8; ++kk) {
        bf16x8_t afr[4];
        #pragma unroll
        for (int mt = 0; mt < 4; ++mt)
            afr[mt] = *(const bf16x8_t*)&bufR[mt * 16 + ln15][kk * 32 + quad * 8];
        #pragma unroll
        for (int ntl = 0; ntl < 4; ++ntl) {
            int nt = w * 4 + ntl;
            bf16x8_t bfr = *(const bf16x8_t*)(pmw2F + ((nt * 8 + kk) * 64 + lane) * 8);
            #pragma unroll
            for (int mt = 0; mt < 4; ++mt)
                acc[ntl][mt] = __builtin_amdgcn_mfma_f32_16x16x32_bf16(afr[mt], bfr, acc[ntl][mt], 0, 0, 0);
        }
    }
    __syncthreads();                           // h1 reads done
    // pem epilogue -> bufR
    #pragma unroll
    for (int ntl = 0; ntl < 4; ++ntl) {
        int c = (w * 4 + ntl) * 16 + ln15;
        float bb = bias2[1][c];
        for (int mt = 0; mt < 4; ++mt)
            for (int r = 0; r < 4; ++r)
                bufR[mt * 16 + quad * 4 + r][c] = f2b(acc[ntl][mt][r] + bb);
    }
    __syncthreads();

    // ---- phase 3: r = (k - q) * pem + peb ; we1T fill ----
    if (t < 64) {
        int g = t >> 3, j8 = t & 7;
        for (int i = 0; i < 32; ++i) {
            int c = j8 * 32 + i;
            we1T[g][c] = f2b(we_w1[c * 8 + g]);
        }
    }
    {
        const unsigned short* qrow = qm + Pg3 * 256 + c3;
        #pragma unroll
        for (int i = 0; i < 8; ++i) {
            int c = c3 + 32 * i;
            uint4 qb  = *(const uint4*)(qrow + 32 * i);
            uint4 pmv = *(const uint4*)&bufR[m3][c];
            uint4 pbv = *(const uint4*)&bufP[m3][c];
            uint4 r;
            r.x = relpair(kpre[i].x, qb.x, pmv.x, pbv.x);
            r.y = relpair(kpre[i].y, qb.y, pmv.y, pbv.y);
            r.z = relpair(kpre[i].z, qb.z, pmv.z, pbv.z);
            r.w = relpair(kpre[i].w, qb.w, pmv.w, pbv.w);
            *(uint4*)&bufR[m3][c] = r;
        }
    }
    __syncthreads();

    // ---- phase 4a: logits GEMM ----
    {
        const bf16x8_t bz = {0, 0, 0, 0, 0, 0, 0, 0};
        f32x4_t lacc = fzero;
        #pragma unroll
        for (int kk = 0; kk < 8; ++kk) {
            bf16x8_t afr = *(const bf16x8_t*)&bufR[mrow][kk * 32 + quad * 8];
            bf16x8_t bfr = bz;
            if (ln15 < 8) bfr = *(const bf16x8_t*)&we1T[ln15][kk * 32 + quad * 8];
            lacc = __builtin_amdgcn_mfma_f32_16x16x32_bf16(afr, bfr, lacc, 0, 0, 0);
        }
        if (ln15 < 8) {
            float sc = swe[ln15], dd = dwe[ln15];
            for (int r = 0; r < 4; ++r)
                us_[w * 16 + quad * 4 + r][ln15] = fmaxf(lacc[r] * sc + dd, 0.f);
        }
    }
    __syncthreads();

    // ---- phase 4b ----
    if (t < 64) {
        float uv[8];
        for (int gp = 0; gp < 8; ++gp) uv[gp] = us_[t][gp];
        for (int g = 0; g < 8; ++g) {
            float l = web2[g];
            for (int gp = 0; gp < 8; ++gp) l += uv[gp] * we2s[gp][g];
            lg_[t][g] = l;
        }
    }
    __syncthreads();

    // ---- phase 4c: softmax ----
    if (t < 32) {
        int p = t >> 3, g = t & 7;
        float mx = -1e30f;
        for (int s = 0; s < 16; ++s) mx = fmaxf(mx, lg_[p * 16 + s][g]);
        float e[16], sum = 0.f;
        for (int s = 0; s < 16; ++s) { e[s] = __expf(lg_[p * 16 + s][g] - mx); sum += e[s]; }
        float inv = 1.f / sum;
        for (int s = 0; s < 16; ++s) lg_[p * 16 + s][g] = e[s] * inv;
    }
    __syncthreads();

    // ---- phase 5: out (v prefetched) ----
    {
        int g = c5 >> 5;
        float a0 = 0.f, a1 = 0.f, a2 = 0.f, a3 = 0.f;
        #pragma unroll
        for (int s = 0; s < 16; ++s) {
            int m = p5 * 16 + s;
            float wv_ = lg_[m][g];
            uint2 v4 = vpre[s];
            uint2 p4 = *(const uint2*)&bufP[m][c5];
            a0 += wv_ * (b2f(v4.x & 0xffffu) + b2f(p4.x & 0xffffu));
            a1 += wv_ * (b2f(v4.x >> 16)     + b2f(p4.x >> 16));
            a2 += wv_ * (b2f(v4.y & 0xffffu) + b2f(p4.y & 0xffffu));
            a3 += wv_ * (b2f(v4.y >> 16)     + b2f(p4.y >> 16));
        }
        *(float4*)(out + (size_t)(P0 + p5) * 256 + c5) = make_float4(a0, a1, a2, a3);
    }
}

// ---------------------------------------------------------------------------
extern "C" void kernel_launch(void* const* d_in, const int* in_sizes, int n_in,
                              void* d_out, int out_size, void* d_ws, size_t ws_size,
                              hipStream_t stream)
{
    const float* feats  = (const float*)d_in[0];
    const float* coords = (const float*)d_in[1];
    const int*   index  = (const int*)d_in[2];
    const float* wq     = (const float*)d_in[3];
    const float* bq     = (const float*)d_in[4];
    const float* bnq    = (const float*)d_in[5];
    const float* wk     = (const float*)d_in[6];
    const float* bk     = (const float*)d_in[7];
    const float* bnk    = (const float*)d_in[8];
    const float* wv     = (const float*)d_in[9];
    const float* bv     = (const float*)d_in[10];
    const float* pm_w1  = (const float*)d_in[11];
    const float* pm_b1  = (const float*)d_in[12];
    const float* pm_bn  = (const float*)d_in[13];
    const float* pm_w2  = (const float*)d_in[14];
    const float* pm_b2  = (const float*)d_in[15];
    const float* pb_w1  = (const float*)d_in[16];
    const float* pb_b1  = (const float*)d_in[17];
    const float* pb_bn  = (const float*)d_in[18];
    const float* pb_w2  = (const float*)d_in[19];
    const float* pb_b2  = (const float*)d_in[20];
    const float* we_w1  = (const float*)d_in[21];
    const float* we_b1  = (const float*)d_in[22];
    const float* we_bn  = (const float*)d_in[23];
    const float* we_w2  = (const float*)d_in[24];
    const float* we_b2  = (const float*)d_in[25];

    unsigned short* qkv = (unsigned short*)d_ws;
    unsigned short* wsT = qkv + (size_t)3 * 8192 * 256;

    const size_t need = ((size_t)3 * 8192 * 256 + (size_t)5 * 65536) * 2;
    if (ws_size < need) {
        hipMemsetAsync(d_out, 0, (size_t)out_size * 4, stream);
        return;
    }

    k_prep<<<5 * 256, 256, 0, stream>>>(wq, wk, wv, pm_w2, pb_w2, wsT);
    k_qkv <<<768,     256, 0, stream>>>(feats, wsT, bq, bnq, bk, bnk, bv, qkv);
    k_main<<<2048,    256, 0, stream>>>(coords, index,
                                        qkv,
                                        qkv + (size_t)8192 * 256,
                                        qkv + (size_t)2 * 8192 * 256,
                                        wsT + 3 * 65536,
                                        wsT + 4 * 65536,
                                        pm_w1, pm_b1, pm_bn, pm_b2,
                                        pb_w1, pb_b1, pb_bn, pb_b2,
                                        we_w1, we_b1, we_bn, we_w2, we_b2,
                                        (float*)d_out);
}